// Round 1
// baseline (1122.057 us; speedup 1.0000x reference)
//
#include <hip/hip_runtime.h>
#include <math.h>

// FNO-3D spectral convolution via separable partial DFTs (no full FFT).
// x: (16,192,192,192) f32; wr/wi: (4,16,16,16,16,16) f32; out: (16,192,192,192) f32.
// Only 32x32x16 frequency modes are nonzero after mode truncation, so:
//  K1: z-DFT  (192 -> 16 modes, real input)   A[c][x][y][kz]      75.5 MB
//  K2: y-DFT  (192 -> 32 modes)               B[c][x][ky][kz]     12.6 MB
//  K3: x-DFT  (192 -> 32 modes)               Xf[c][kx][ky][kz]    2.1 MB
//  K4: channel mix + fold (eps_kz / N^3)      Y[o][kx][ky][kz]     2.1 MB
//  K5: inverse x-expand (32 -> 192)           G1 (reuses B slot)
//  K6: inverse y-expand (32 -> 192)           G2 (reuses A slot)
//  K7: inverse z-expand + Re(.)  -> out (453 MB)
// ws peak = 92.3 MB.

#define NN 192
#define NC 16
#define NM 16
#define NK2 32

constexpr float TWOPI  = 6.283185307179586476925286766559f;
constexpr float INV_N3 = 1.0f / (192.0f * 192.0f * 192.0f);

__device__ __forceinline__ void fill_T(float2* T) {
  int t = threadIdx.x;
  if (t < NN) {
    float s, c;
    sincosf((TWOPI / NN) * (float)t, &s, &c);
    T[t] = make_float2(c, s);   // (cos, +sin); signs handled per stage
  }
}

// ---------------- K1: forward z-DFT (real -> 16 complex modes) ----------------
// 64 rows/block; thread (kz = t&15, grp = t>>4) accumulates 4 rows x 1 kz.
// xs stride 193: fixed (r,z) across grps -> bank stride 4 -> 2-way conflict (free).
__global__ __launch_bounds__(256) void k1_fwd_z(const float* __restrict__ x,
                                                float2* __restrict__ A) {
  __shared__ float xs[64 * 193];
  __shared__ float2 T[NN];
  const int t = threadIdx.x;
  fill_T(T);
  const int rowBase = blockIdx.x * 64;
  const float4* src = (const float4*)(x + (size_t)rowBase * NN);
#pragma unroll
  for (int k = 0; k < 12; ++k) {
    int i = t + k * 256;            // float4 index < 3072
    float4 v = src[i];
    int fi = i << 2;
    int row = fi / NN;
    int z = fi - row * NN;          // multiple of 4, same row for all 4
    float* d = &xs[row * 193 + z];
    d[0] = v.x; d[1] = v.y; d[2] = v.z; d[3] = v.w;
  }
  __syncthreads();
  const int kz = t & 15;
  const int r0 = (t >> 4) << 2;
  float ar[4] = {0.f, 0.f, 0.f, 0.f};
  float ai[4] = {0.f, 0.f, 0.f, 0.f};
  int p = 0;                        // p = (kz*z) % 192
#pragma unroll 8
  for (int z = 0; z < NN; ++z) {
    float2 w = T[p];
    p += kz; p = (p >= NN) ? p - NN : p;
#pragma unroll
    for (int r = 0; r < 4; ++r) {
      float xv = xs[(r0 + r) * 193 + z];
      ar[r] = fmaf(xv, w.x, ar[r]);       // e^{-i th}: (+cos)
      ai[r] = fmaf(-xv, w.y, ai[r]);      //            (-sin)
    }
  }
  float2* dst = A + (size_t)rowBase * NM;
#pragma unroll
  for (int r = 0; r < 4; ++r)
    dst[(r0 + r) * NM + kz] = make_float2(ar[r], ai[r]);
}

// ---------------- K2: forward y-DFT (192 -> 32 modes), complex ----------------
__global__ __launch_bounds__(256) void k2_fwd_y(const float2* __restrict__ A,
                                                float2* __restrict__ B) {
  __shared__ __align__(16) float2 As[NN * NM];   // 24 KB
  __shared__ float2 T[NN];
  const int t = threadIdx.x;
  fill_T(T);
  const int cx = blockIdx.x;                     // c*192 + x
  const float4* src = (const float4*)(A + (size_t)cx * NN * NM);
  float4* dl = (float4*)As;
#pragma unroll
  for (int k = 0; k < 6; ++k) dl[t + k * 256] = src[t + k * 256];
  __syncthreads();
  const int kz = t & 15;
  const int kyq = t >> 4;            // handles ky = kyq and ky = 16+kyq (f = 176+kyq)
  const int s1 = 176 + kyq;
  float2 a0 = make_float2(0.f, 0.f), a1 = make_float2(0.f, 0.f);
  int p0 = 0, p1 = 0;
#pragma unroll 4
  for (int y = 0; y < NN; ++y) {
    float2 a = As[y * NM + kz];
    float2 w0 = T[p0]; p0 += kyq; p0 = (p0 >= NN) ? p0 - NN : p0;
    float2 w1 = T[p1]; p1 += s1;  p1 = (p1 >= NN) ? p1 - NN : p1;
    // (Ar+iAi)(cos - i sin): Br += Ar c + Ai s ; Bi += Ai c - Ar s
    a0.x = fmaf(a.x, w0.x, fmaf(a.y, w0.y, a0.x));
    a0.y = fmaf(a.y, w0.x, fmaf(-a.x, w0.y, a0.y));
    a1.x = fmaf(a.x, w1.x, fmaf(a.y, w1.y, a1.x));
    a1.y = fmaf(a.y, w1.x, fmaf(-a.x, w1.y, a1.y));
  }
  float2* dst = B + (size_t)cx * NK2 * NM;
  dst[kyq * NM + kz] = a0;
  dst[(16 + kyq) * NM + kz] = a1;
}

// ---------------- K3: forward x-DFT (192 -> 32 modes), complex ----------------
__global__ __launch_bounds__(256) void k3_fwd_x(const float2* __restrict__ B,
                                                float2* __restrict__ Xf) {
  __shared__ __align__(16) float2 Bs[NN * NM];
  __shared__ float2 T[NN];
  const int t = threadIdx.x;
  fill_T(T);
  const int c = blockIdx.x >> 5, ky = blockIdx.x & 31;
#pragma unroll
  for (int k = 0; k < 6; ++k) {
    int i = t + k * 256;            // float4 index < 1536; i = xx*8 + q
    int xx = i >> 3, q = i & 7;
    ((float4*)Bs)[i] = *((const float4*)(B + ((size_t)(c * NN + xx) * NK2 + ky) * NM) + q);
  }
  __syncthreads();
  const int kz = t & 15, kxq = t >> 4;
  const int s1 = 176 + kxq;
  float2 a0 = make_float2(0.f, 0.f), a1 = make_float2(0.f, 0.f);
  int p0 = 0, p1 = 0;
#pragma unroll 4
  for (int xx = 0; xx < NN; ++xx) {
    float2 b = Bs[xx * NM + kz];
    float2 w0 = T[p0]; p0 += kxq; p0 = (p0 >= NN) ? p0 - NN : p0;
    float2 w1 = T[p1]; p1 += s1;  p1 = (p1 >= NN) ? p1 - NN : p1;
    a0.x = fmaf(b.x, w0.x, fmaf(b.y, w0.y, a0.x));
    a0.y = fmaf(b.y, w0.x, fmaf(-b.x, w0.y, a0.y));
    a1.x = fmaf(b.x, w1.x, fmaf(b.y, w1.y, a1.x));
    a1.y = fmaf(b.y, w1.x, fmaf(-b.x, w1.y, a1.y));
  }
  Xf[((size_t)(c * NK2 + kxq) * NK2 + ky) * NM + kz] = a0;
  Xf[((size_t)(c * NK2 + 16 + kxq) * NK2 + ky) * NM + kz] = a1;
}

// ---------------- K4: channel mix + scale fold ----------------
// thread <-> mode (16384 = 32kx * 32ky * 16kz); eps_kz/N^3 folded here.
__global__ __launch_bounds__(256) void k4_mix(const float2* __restrict__ Xf,
                                              const float* __restrict__ wr,
                                              const float* __restrict__ wi,
                                              float2* __restrict__ Y) {
  const int tm = blockIdx.x * 256 + threadIdx.x;
  const int kz = tm & 15, ky = (tm >> 4) & 31, kx = tm >> 9;
  const int q = (kx >= 16 ? 1 : 0) + (ky >= 16 ? 2 : 0);
  const int modeW = ((kx & 15) * 16 + (ky & 15)) * 16 + kz;
  float xr[NC], xi[NC];
#pragma unroll
  for (int i = 0; i < NC; ++i) {
    float2 v = Xf[i * 16384 + tm];
    xr[i] = v.x; xi[i] = v.y;
  }
  const float scale = (kz == 0 ? 1.0f : 2.0f) * INV_N3;
#pragma unroll 1
  for (int o = 0; o < NC; ++o) {
    float cr = 0.f, ci = 0.f;
#pragma unroll
    for (int i = 0; i < NC; ++i) {
      size_t wIdx = (size_t)((q * 16 + i) * 16 + o) * 4096 + modeW;
      float a = wr[wIdx], b = wi[wIdx];
      cr = fmaf(xr[i], a, fmaf(-xi[i], b, cr));
      ci = fmaf(xr[i], b, fmaf(xi[i], a, ci));
    }
    Y[o * 16384 + tm] = make_float2(cr * scale, ci * scale);
  }
}

// ---------------- K5: inverse x-expand (32 modes -> 192) ----------------
__global__ __launch_bounds__(256) void k5_inv_x(const float2* __restrict__ Y,
                                                float2* __restrict__ G1) {
  __shared__ __align__(16) float2 Ys[NK2 * NM];
  __shared__ float2 T[NN];
  const int t = threadIdx.x;
  fill_T(T);
  const int c = blockIdx.x >> 5, ky = blockIdx.x & 31;
  {
    int kx = t >> 3, qq = t & 7;
    ((float4*)Ys)[t] = *((const float4*)(Y + (size_t)c * 16384 + (size_t)kx * (NK2 * NM) + ky * NM) + qq);
  }
  __syncthreads();
  const int kz = t & 15, xq = t >> 4;
#pragma unroll 1
  for (int j = 0; j < 12; ++j) {
    const int xx = xq + 16 * j;
    float2 acc = make_float2(0.f, 0.f);
    const int step = xx;
    int p = 0;                       // f=kx half: p = kx*xx mod 192
#pragma unroll
    for (int k = 0; k < 16; ++k) {
      float2 v = Ys[k * NM + kz];
      float2 w = T[p]; p += step; p = (p >= NN) ? p - NN : p;
      // e^{+i th}: Gr += Yr c - Yi s ; Gi += Yi c + Yr s
      acc.x = fmaf(v.x, w.x, fmaf(-v.y, w.y, acc.x));
      acc.y = fmaf(v.y, w.x, fmaf( v.x, w.y, acc.y));
    }
    int p2 = (176 * xx) % NN;        // f=176+k half
#pragma unroll
    for (int k = 0; k < 16; ++k) {
      float2 v = Ys[(16 + k) * NM + kz];
      float2 w = T[p2]; p2 += step; p2 = (p2 >= NN) ? p2 - NN : p2;
      acc.x = fmaf(v.x, w.x, fmaf(-v.y, w.y, acc.x));
      acc.y = fmaf(v.y, w.x, fmaf( v.x, w.y, acc.y));
    }
    G1[((size_t)(c * NN + xx) * NK2 + ky) * NM + kz] = acc;
  }
}

// ---------------- K6: inverse y-expand (32 modes -> 192) ----------------
__global__ __launch_bounds__(256) void k6_inv_y(const float2* __restrict__ G1,
                                                float2* __restrict__ G2) {
  __shared__ __align__(16) float2 Gs[NK2 * NM];
  __shared__ float2 T[NN];
  const int t = threadIdx.x;
  fill_T(T);
  const int cx = blockIdx.x;                   // c*192 + x
  ((float4*)Gs)[t] = ((const float4*)(G1 + (size_t)cx * NK2 * NM))[t];
  __syncthreads();
  const int kz = t & 15, yq = t >> 4;
#pragma unroll 1
  for (int j = 0; j < 12; ++j) {
    const int y = yq + 16 * j;
    float2 acc = make_float2(0.f, 0.f);
    const int step = y;
    int p = 0;
#pragma unroll
    for (int k = 0; k < 16; ++k) {
      float2 v = Gs[k * NM + kz];
      float2 w = T[p]; p += step; p = (p >= NN) ? p - NN : p;
      acc.x = fmaf(v.x, w.x, fmaf(-v.y, w.y, acc.x));
      acc.y = fmaf(v.y, w.x, fmaf( v.x, w.y, acc.y));
    }
    int p2 = (176 * y) % NN;
#pragma unroll
    for (int k = 0; k < 16; ++k) {
      float2 v = Gs[(16 + k) * NM + kz];
      float2 w = T[p2]; p2 += step; p2 = (p2 >= NN) ? p2 - NN : p2;
      acc.x = fmaf(v.x, w.x, fmaf(-v.y, w.y, acc.x));
      acc.y = fmaf(v.y, w.x, fmaf( v.x, w.y, acc.y));
    }
    G2[((size_t)cx * NN + y) * NM + kz] = acc;
  }
}

// ---------------- K7: inverse z-expand, real output ----------------
// out[.,y,z] = sum_kz ( Gr*cos - Gi*sin ), eps/N^3 already folded into Y.
__global__ __launch_bounds__(192) void k7_inv_z(const float2* __restrict__ G2,
                                                float* __restrict__ out) {
  __shared__ __align__(16) float2 Gs[NN * NM];  // 24 KB
  __shared__ float2 T[NN];
  const int t = threadIdx.x;                    // 0..191 == z
  fill_T(T);
  const int cx = blockIdx.x;
  const float4* src = (const float4*)(G2 + (size_t)cx * NN * NM);  // 1536 f4
#pragma unroll
  for (int k = 0; k < 8; ++k) ((float4*)Gs)[t + k * 192] = src[t + k * 192];
  __syncthreads();
  const int z = t;
  float twc[16], tws[16];
#pragma unroll
  for (int kz = 0; kz < 16; ++kz) {
    float2 w = T[(kz * z) % NN];
    twc[kz] = w.x; tws[kz] = w.y;
  }
  const float4* Gs4 = (const float4*)Gs;
  float* obase = out + (size_t)cx * NN * NN;
#pragma unroll 2
  for (int y = 0; y < NN; ++y) {
    float acc = 0.f;
#pragma unroll
    for (int h = 0; h < 8; ++h) {
      float4 g = Gs4[y * 8 + h];
      acc = fmaf(g.x, twc[2 * h],     fmaf(-g.y, tws[2 * h],     acc));
      acc = fmaf(g.z, twc[2 * h + 1], fmaf(-g.w, tws[2 * h + 1], acc));
    }
    obase[y * NN + z] = acc;
  }
}

extern "C" void kernel_launch(void* const* d_in, const int* in_sizes, int n_in,
                              void* d_out, int out_size, void* d_ws, size_t ws_size,
                              hipStream_t stream) {
  const float* x  = (const float*)d_in[0];
  const float* wr = (const float*)d_in[1];
  const float* wi = (const float*)d_in[2];
  float* out = (float*)d_out;

  // workspace layout (float2 units); G1 reuses B, G2 reuses A. Peak 92.3 MB.
  float2* A  = (float2*)d_ws;          // 9437184 fl2
  float2* B  = A  + 9437184;           // 1572864 fl2
  float2* Xf = B  + 1572864;           //  262144 fl2
  float2* Y  = Xf + 262144;            //  262144 fl2
  float2* G1 = B;
  float2* G2 = A;

  k1_fwd_z<<<dim3(9216), dim3(256), 0, stream>>>(x, A);
  k2_fwd_y<<<dim3(3072), dim3(256), 0, stream>>>(A, B);
  k3_fwd_x<<<dim3(512),  dim3(256), 0, stream>>>(B, Xf);
  k4_mix  <<<dim3(64),   dim3(256), 0, stream>>>(Xf, wr, wi, Y);
  k5_inv_x<<<dim3(512),  dim3(256), 0, stream>>>(Y, G1);
  k6_inv_y<<<dim3(3072), dim3(256), 0, stream>>>(G1, G2);
  k7_inv_z<<<dim3(3072), dim3(192), 0, stream>>>(G2, out);
}